// Round 1
// baseline (73.092 us; speedup 1.0000x reference)
//
#include <hip/hip_runtime.h>
#include <hip/hip_bf16.h>
#include <math.h>

#define BB 32
#define NN 2048
#define BLK 256
#define TILES (NN / BLK)   // 8

__global__ __launch_bounds__(BLK) void chamfer_bce_kernel(
    const float* __restrict__ est, const float* __restrict__ gt,
    const float* __restrict__ lest, const float* __restrict__ lab,
    float* __restrict__ out) {
  // gridDim.x = 2 * BB * TILES. First half: est->gt (+BCE). Second half: gt->est.
  int bid = blockIdx.x;
  int dir = (bid >= BB * TILES) ? 1 : 0;
  int id = dir ? (bid - BB * TILES) : bid;
  int b = id / TILES;
  int tile = id % TILES;

  const float* X = dir ? gt : est;   // query points
  const float* Y = dir ? est : gt;   // target set

  __shared__ float4 sy[NN];          // 32 KB
  const float* yb = Y + (size_t)b * NN * 3;
  for (int j = threadIdx.x; j < NN; j += BLK) {
    float a = yb[3 * j + 0];
    float c = yb[3 * j + 1];
    float d = yb[3 * j + 2];
    sy[j] = make_float4(a, c, d, 0.0f);
  }
  __syncthreads();

  int i = tile * BLK + threadIdx.x;
  const float* xb = X + (size_t)b * NN * 3 + (size_t)3 * i;
  float ex = xb[0], ey = xb[1], ez = xb[2];

  float m0 = 3.4e38f, m1 = 3.4e38f, m2 = 3.4e38f, m3 = 3.4e38f;
#pragma unroll 4
  for (int j = 0; j < NN; j += 4) {
    float4 p0 = sy[j + 0];
    float4 p1 = sy[j + 1];
    float4 p2 = sy[j + 2];
    float4 p3 = sy[j + 3];
    {
      float dx = ex - p0.x, dy = ey - p0.y, dz = ez - p0.z;
      float d2 = fmaf(dx, dx, fmaf(dy, dy, dz * dz));
      m0 = fminf(m0, d2);
    }
    {
      float dx = ex - p1.x, dy = ey - p1.y, dz = ez - p1.z;
      float d2 = fmaf(dx, dx, fmaf(dy, dy, dz * dz));
      m1 = fminf(m1, d2);
    }
    {
      float dx = ex - p2.x, dy = ey - p2.y, dz = ez - p2.z;
      float d2 = fmaf(dx, dx, fmaf(dy, dy, dz * dz));
      m2 = fminf(m2, d2);
    }
    {
      float dx = ex - p3.x, dy = ey - p3.y, dz = ez - p3.z;
      float d2 = fmaf(dx, dx, fmaf(dy, dy, dz * dz));
      m3 = fminf(m3, d2);
    }
  }
  float val = fminf(fminf(m0, m1), fminf(m2, m3));

  if (!dir) {
    // fuse BCE for element (b, i): max(z,0) - z*t + log1p(exp(-|z|))
    float z = lest[(size_t)b * NN + i];
    float t = lab[(size_t)b * NN + i];
    float bce = fmaxf(z, 0.0f) - z * t + log1pf(expf(-fabsf(z)));
    val += bce;
  }

  // block reduction (sum), then one atomicAdd scaled by 1/(B*N)
  for (int off = 32; off > 0; off >>= 1) val += __shfl_down(val, off);
  __shared__ float wsum[BLK / 64];
  int lane = threadIdx.x & 63;
  int wid = threadIdx.x >> 6;
  if (lane == 0) wsum[wid] = val;
  __syncthreads();
  if (threadIdx.x == 0) {
    float s = 0.0f;
#pragma unroll
    for (int w = 0; w < BLK / 64; ++w) s += wsum[w];
    atomicAdd(out, s * (1.0f / ((float)BB * (float)NN)));
  }
}

extern "C" void kernel_launch(void* const* d_in, const int* in_sizes, int n_in,
                              void* d_out, int out_size, void* d_ws, size_t ws_size,
                              hipStream_t stream) {
  const float* est = (const float*)d_in[0];
  const float* gt = (const float*)d_in[1];
  const float* lest = (const float*)d_in[2];
  const float* lab = (const float*)d_in[3];
  float* out = (float*)d_out;

  hipMemsetAsync(out, 0, sizeof(float), stream);
  dim3 grid(2 * BB * TILES);
  dim3 block(BLK);
  chamfer_bce_kernel<<<grid, block, 0, stream>>>(est, gt, lest, lab, out);
}

// Round 2
// 40.340 us; speedup vs baseline: 1.8119x; 1.8119x over previous
//
#include <hip/hip_runtime.h>
#include <hip/hip_bf16.h>
#include <math.h>

#define BB 32
#define NN 2048
#define BLK 256
#define JC 16
#define JCH (NN / JC)        // 128 points staged per block (2 KB LDS)
#define IPP 4                // queries per thread
#define ITILE (BLK * IPP)    // 1024
#define ITILES (NN / ITILE)  // 2

// Order-preserving float<->uint encode for bitwise atomicMin.
__device__ __forceinline__ unsigned fkey(float f) {
  unsigned u = __float_as_uint(f);
  return (u & 0x80000000u) ? ~u : (u | 0x80000000u);
}
__device__ __forceinline__ float funkey(unsigned k) {
  return (k & 0x80000000u) ? __uint_as_float(k & 0x7FFFFFFFu)
                           : __uint_as_float(~k);
}

// Pass 1: per (dir, b, i) compute min_j (|y_j|^2/2 - x_i . y_j) over this
// block's j-chunk; combine across j-chunk blocks with bitwise atomicMin.
__global__ __launch_bounds__(BLK) void cham_min_kernel(
    const float* __restrict__ est, const float* __restrict__ gt,
    unsigned* __restrict__ wkey) {
  int id = blockIdx.x;
  int jc = id % JC; id /= JC;
  int it = id % ITILES; id /= ITILES;
  int b = id % BB;
  int dir = id / BB;

  const float* X = dir ? gt : est;   // query set
  const float* Y = dir ? est : gt;   // target set

  __shared__ float4 sy[JCH];         // (-yx, -yy, -yz, |y|^2/2)
  {
    int t = threadIdx.x;
    if (t < JCH) {
      const float* yp = Y + ((size_t)b * NN + (size_t)jc * JCH + t) * 3;
      float yx = yp[0], yy = yp[1], yz = yp[2];
      float h = 0.5f * (yx * yx + yy * yy + yz * yz);
      sy[t] = make_float4(-yx, -yy, -yz, h);
    }
  }
  __syncthreads();

  float ex[IPP], ey[IPP], ez[IPP], mn[IPP];
  int ibase = it * ITILE + threadIdx.x;
#pragma unroll
  for (int k = 0; k < IPP; ++k) {
    const float* xp = X + ((size_t)b * NN + ibase + k * BLK) * 3;
    ex[k] = xp[0]; ey[k] = xp[1]; ez[k] = xp[2];
    mn[k] = 3.4e38f;
  }

#pragma unroll 4
  for (int j = 0; j < JCH; ++j) {
    float4 p = sy[j];  // broadcast read: all lanes same addr, conflict-free
#pragma unroll
    for (int k = 0; k < IPP; ++k) {
      float t = fmaf(ex[k], p.x, fmaf(ey[k], p.y, fmaf(ez[k], p.z, p.w)));
      mn[k] = fminf(mn[k], t);
    }
  }

  unsigned* wrow = wkey + ((size_t)dir * BB + b) * NN;
#pragma unroll
  for (int k = 0; k < IPP; ++k)
    atomicMin(&wrow[ibase + k * BLK], fkey(mn[k]));
}

// Pass 2: decode min t, d2 = max(|x|^2 + 2t, 0); fuse BCE on dir==0 half;
// global sum-reduce scaled by 1/(B*N).
__global__ __launch_bounds__(BLK) void finalize_kernel(
    const float* __restrict__ est, const float* __restrict__ gt,
    const float* __restrict__ lest, const float* __restrict__ lab,
    const unsigned* __restrict__ wkey, float* __restrict__ out) {
  int q = blockIdx.x * BLK + threadIdx.x;  // [0, 2*BB*NN)
  int dir = q / (BB * NN);
  int r = q % (BB * NN);
  const float* X = dir ? gt : est;
  const float* xp = X + (size_t)r * 3;
  float ex = xp[0], ey = xp[1], ez = xp[2];
  float x2 = fmaf(ex, ex, fmaf(ey, ey, ez * ez));
  float t = funkey(wkey[q]);
  float val = fmaxf(fmaf(2.0f, t, x2), 0.0f);
  if (!dir) {  // wave-uniform: dir boundary is a multiple of 64
    float z = lest[r], tt = lab[r];
    val += fmaxf(z, 0.0f) - z * tt + log1pf(expf(-fabsf(z)));
  }
  for (int off = 32; off > 0; off >>= 1) val += __shfl_down(val, off);
  __shared__ float wsum[BLK / 64];
  int lane = threadIdx.x & 63;
  int wid = threadIdx.x >> 6;
  if (lane == 0) wsum[wid] = val;
  __syncthreads();
  if (threadIdx.x == 0) {
    float s = 0.0f;
#pragma unroll
    for (int w = 0; w < BLK / 64; ++w) s += wsum[w];
    atomicAdd(out, s * (1.0f / ((float)BB * (float)NN)));
  }
}

// Fallback (proven-correct R1 kernel) if ws is too small for the key array.
__global__ __launch_bounds__(BLK) void chamfer_bce_kernel(
    const float* __restrict__ est, const float* __restrict__ gt,
    const float* __restrict__ lest, const float* __restrict__ lab,
    float* __restrict__ out) {
  int bid = blockIdx.x;
  int dir = (bid >= BB * (NN / BLK)) ? 1 : 0;
  int id = dir ? (bid - BB * (NN / BLK)) : bid;
  int b = id / (NN / BLK);
  int tile = id % (NN / BLK);
  const float* X = dir ? gt : est;
  const float* Y = dir ? est : gt;
  __shared__ float4 sy[NN];
  const float* yb = Y + (size_t)b * NN * 3;
  for (int j = threadIdx.x; j < NN; j += BLK) {
    sy[j] = make_float4(yb[3 * j], yb[3 * j + 1], yb[3 * j + 2], 0.0f);
  }
  __syncthreads();
  int i = tile * BLK + threadIdx.x;
  const float* xb = X + (size_t)b * NN * 3 + (size_t)3 * i;
  float ex = xb[0], ey = xb[1], ez = xb[2];
  float m0 = 3.4e38f, m1 = 3.4e38f, m2 = 3.4e38f, m3 = 3.4e38f;
#pragma unroll 4
  for (int j = 0; j < NN; j += 4) {
    float4 p0 = sy[j], p1 = sy[j + 1], p2 = sy[j + 2], p3 = sy[j + 3];
    { float dx = ex - p0.x, dy = ey - p0.y, dz = ez - p0.z;
      m0 = fminf(m0, fmaf(dx, dx, fmaf(dy, dy, dz * dz))); }
    { float dx = ex - p1.x, dy = ey - p1.y, dz = ez - p1.z;
      m1 = fminf(m1, fmaf(dx, dx, fmaf(dy, dy, dz * dz))); }
    { float dx = ex - p2.x, dy = ey - p2.y, dz = ez - p2.z;
      m2 = fminf(m2, fmaf(dx, dx, fmaf(dy, dy, dz * dz))); }
    { float dx = ex - p3.x, dy = ey - p3.y, dz = ez - p3.z;
      m3 = fminf(m3, fmaf(dx, dx, fmaf(dy, dy, dz * dz))); }
  }
  float val = fminf(fminf(m0, m1), fminf(m2, m3));
  if (!dir) {
    float z = lest[(size_t)b * NN + i];
    float t = lab[(size_t)b * NN + i];
    val += fmaxf(z, 0.0f) - z * t + log1pf(expf(-fabsf(z)));
  }
  for (int off = 32; off > 0; off >>= 1) val += __shfl_down(val, off);
  __shared__ float wsum[BLK / 64];
  int lane = threadIdx.x & 63;
  int wid = threadIdx.x >> 6;
  if (lane == 0) wsum[wid] = val;
  __syncthreads();
  if (threadIdx.x == 0) {
    float s = 0.0f;
#pragma unroll
    for (int w = 0; w < BLK / 64; ++w) s += wsum[w];
    atomicAdd(out, s * (1.0f / ((float)BB * (float)NN)));
  }
}

extern "C" void kernel_launch(void* const* d_in, const int* in_sizes, int n_in,
                              void* d_out, int out_size, void* d_ws, size_t ws_size,
                              hipStream_t stream) {
  const float* est = (const float*)d_in[0];
  const float* gt = (const float*)d_in[1];
  const float* lest = (const float*)d_in[2];
  const float* lab = (const float*)d_in[3];
  float* out = (float*)d_out;

  hipMemsetAsync(out, 0, sizeof(float), stream);

  const size_t need = (size_t)2 * BB * NN * sizeof(unsigned);  // 512 KB
  if (ws_size >= need) {
    unsigned* wkey = (unsigned*)d_ws;
    hipMemsetAsync(wkey, 0xFF, need, stream);  // 0xFFFFFFFF = max key
    cham_min_kernel<<<dim3(2 * BB * ITILES * JC), dim3(BLK), 0, stream>>>(
        est, gt, wkey);
    finalize_kernel<<<dim3((2 * BB * NN) / BLK), dim3(BLK), 0, stream>>>(
        est, gt, lest, lab, wkey, out);
  } else {
    chamfer_bce_kernel<<<dim3(2 * BB * (NN / BLK)), dim3(BLK), 0, stream>>>(
        est, gt, lest, lab, out);
  }
}

// Round 3
// 33.752 us; speedup vs baseline: 2.1656x; 1.1952x over previous
//
#include <hip/hip_runtime.h>
#include <hip/hip_bf16.h>
#include <math.h>

#define BB 32
#define NN 2048
#define BLK 256
#define JC 16
#define JCH (NN / JC)   // 128 target points staged per block (2 KB LDS)
#define IPP 8           // queries per thread (256*8 = 2048 = all of N)
#define BBNN (BB * NN)  // 65536
#define FIN_BLOCKS ((2 * BBNN) / BLK)  // 512

// Pass 1: block (dir,b,jc) computes, for every query i in [0,2048),
// min over its 128-point j-chunk of t = |y|^2/2 - x.y, and stores the
// partial to part[(jc*2+dir)*BBNN + b*NN + i]. Plain stores, no atomics.
__global__ __launch_bounds__(BLK) void cham_min_kernel(
    const float* __restrict__ est, const float* __restrict__ gt,
    float* __restrict__ part) {
  int id = blockIdx.x;
  int jc = id % JC; id /= JC;
  int b = id % BB;
  int dir = id / BB;

  const float* X = dir ? gt : est;   // query set
  const float* Y = dir ? est : gt;   // target set

  __shared__ float4 sy[JCH];         // (-yx, -yy, -yz, |y|^2/2)
  if (threadIdx.x < JCH) {
    const float* yp = Y + ((size_t)b * NN + (size_t)jc * JCH + threadIdx.x) * 3;
    float yx = yp[0], yy = yp[1], yz = yp[2];
    sy[threadIdx.x] = make_float4(-yx, -yy, -yz,
                                  0.5f * (yx * yx + yy * yy + yz * yz));
  }
  __syncthreads();

  float ex[IPP], ey[IPP], ez[IPP], mn[IPP];
#pragma unroll
  for (int k = 0; k < IPP; ++k) {
    const float* xp = X + ((size_t)b * NN + threadIdx.x + k * BLK) * 3;
    ex[k] = xp[0]; ey[k] = xp[1]; ez[k] = xp[2];
    mn[k] = 3.4e38f;
  }

#pragma unroll 2
  for (int j = 0; j < JCH; ++j) {
    float4 p = sy[j];  // broadcast: all lanes same address, conflict-free
#pragma unroll
    for (int k = 0; k < IPP; ++k) {
      float t = fmaf(ex[k], p.x, fmaf(ey[k], p.y, fmaf(ez[k], p.z, p.w)));
      mn[k] = fminf(mn[k], t);
    }
  }

  float* prow = part + ((size_t)(jc * 2 + dir) * BB + b) * NN;
#pragma unroll
  for (int k = 0; k < IPP; ++k)
    prow[threadIdx.x + k * BLK] = mn[k];
}

// Pass 2: min over the 16 jc-partials, d2 = max(|x|^2 + 2t, 0), fuse BCE
// on the dir==0 half, write one partial sum per block (no atomics).
__global__ __launch_bounds__(BLK) void finalize_kernel(
    const float* __restrict__ est, const float* __restrict__ gt,
    const float* __restrict__ lest, const float* __restrict__ lab,
    const float* __restrict__ part, float* __restrict__ bsum) {
  int q = blockIdx.x * BLK + threadIdx.x;  // [0, 2*BBNN)
  int dir = q / BBNN;                      // uniform per block
  int r = q % BBNN;

  float t = part[(size_t)dir * BBNN + r];
#pragma unroll
  for (int jc = 1; jc < JC; ++jc)
    t = fminf(t, part[(size_t)(jc * 2 + dir) * BBNN + r]);

  const float* xp = (dir ? gt : est) + (size_t)r * 3;
  float ex = xp[0], ey = xp[1], ez = xp[2];
  float x2 = fmaf(ex, ex, fmaf(ey, ey, ez * ez));
  float val = fmaxf(fmaf(2.0f, t, x2), 0.0f);

  if (!dir) {  // wave-uniform branch
    float z = lest[r], tt = lab[r];
    val += fmaxf(z, 0.0f) - z * tt + log1pf(expf(-fabsf(z)));
  }

  for (int off = 32; off > 0; off >>= 1) val += __shfl_down(val, off);
  __shared__ float wsum[BLK / 64];
  int lane = threadIdx.x & 63;
  int wid = threadIdx.x >> 6;
  if (lane == 0) wsum[wid] = val;
  __syncthreads();
  if (threadIdx.x == 0) {
    float s = 0.0f;
#pragma unroll
    for (int w = 0; w < BLK / 64; ++w) s += wsum[w];
    bsum[blockIdx.x] = s;
  }
}

// Pass 3: sum the 512 block partials, scale, store the scalar.
__global__ __launch_bounds__(BLK) void sum_kernel(
    const float* __restrict__ bsum, float* __restrict__ out) {
  float val = bsum[threadIdx.x] + bsum[threadIdx.x + BLK];
  for (int off = 32; off > 0; off >>= 1) val += __shfl_down(val, off);
  __shared__ float wsum[BLK / 64];
  int lane = threadIdx.x & 63;
  int wid = threadIdx.x >> 6;
  if (lane == 0) wsum[wid] = val;
  __syncthreads();
  if (threadIdx.x == 0) {
    float s = 0.0f;
#pragma unroll
    for (int w = 0; w < BLK / 64; ++w) s += wsum[w];
    out[0] = s * (1.0f / ((float)BB * (float)NN));
  }
}

// Fallback (proven-correct R1 kernel) if ws is too small.
__global__ __launch_bounds__(BLK) void chamfer_bce_kernel(
    const float* __restrict__ est, const float* __restrict__ gt,
    const float* __restrict__ lest, const float* __restrict__ lab,
    float* __restrict__ out) {
  int bid = blockIdx.x;
  int dir = (bid >= BB * (NN / BLK)) ? 1 : 0;
  int id = dir ? (bid - BB * (NN / BLK)) : bid;
  int b = id / (NN / BLK);
  int tile = id % (NN / BLK);
  const float* X = dir ? gt : est;
  const float* Y = dir ? est : gt;
  __shared__ float4 sy[NN];
  const float* yb = Y + (size_t)b * NN * 3;
  for (int j = threadIdx.x; j < NN; j += BLK)
    sy[j] = make_float4(yb[3 * j], yb[3 * j + 1], yb[3 * j + 2], 0.0f);
  __syncthreads();
  int i = tile * BLK + threadIdx.x;
  const float* xb = X + (size_t)b * NN * 3 + (size_t)3 * i;
  float ex = xb[0], ey = xb[1], ez = xb[2];
  float m0 = 3.4e38f, m1 = 3.4e38f, m2 = 3.4e38f, m3 = 3.4e38f;
#pragma unroll 4
  for (int j = 0; j < NN; j += 4) {
    float4 p0 = sy[j], p1 = sy[j + 1], p2 = sy[j + 2], p3 = sy[j + 3];
    { float dx = ex - p0.x, dy = ey - p0.y, dz = ez - p0.z;
      m0 = fminf(m0, fmaf(dx, dx, fmaf(dy, dy, dz * dz))); }
    { float dx = ex - p1.x, dy = ey - p1.y, dz = ez - p1.z;
      m1 = fminf(m1, fmaf(dx, dx, fmaf(dy, dy, dz * dz))); }
    { float dx = ex - p2.x, dy = ey - p2.y, dz = ez - p2.z;
      m2 = fminf(m2, fmaf(dx, dx, fmaf(dy, dy, dz * dz))); }
    { float dx = ex - p3.x, dy = ey - p3.y, dz = ez - p3.z;
      m3 = fminf(m3, fmaf(dx, dx, fmaf(dy, dy, dz * dz))); }
  }
  float val = fminf(fminf(m0, m1), fminf(m2, m3));
  if (!dir) {
    float z = lest[(size_t)b * NN + i];
    float t = lab[(size_t)b * NN + i];
    val += fmaxf(z, 0.0f) - z * t + log1pf(expf(-fabsf(z)));
  }
  for (int off = 32; off > 0; off >>= 1) val += __shfl_down(val, off);
  __shared__ float wsum[BLK / 64];
  int lane = threadIdx.x & 63;
  int wid = threadIdx.x >> 6;
  if (lane == 0) wsum[wid] = val;
  __syncthreads();
  if (threadIdx.x == 0) {
    float s = 0.0f;
#pragma unroll
    for (int w = 0; w < BLK / 64; ++w) s += wsum[w];
    atomicAdd(out, s * (1.0f / ((float)BB * (float)NN)));
  }
}

extern "C" void kernel_launch(void* const* d_in, const int* in_sizes, int n_in,
                              void* d_out, int out_size, void* d_ws, size_t ws_size,
                              hipStream_t stream) {
  const float* est = (const float*)d_in[0];
  const float* gt = (const float*)d_in[1];
  const float* lest = (const float*)d_in[2];
  const float* lab = (const float*)d_in[3];
  float* out = (float*)d_out;

  const size_t part_bytes = (size_t)JC * 2 * BBNN * sizeof(float);  // 8 MB
  const size_t need = part_bytes + FIN_BLOCKS * sizeof(float);
  if (ws_size >= need) {
    float* part = (float*)d_ws;
    float* bsum = (float*)((char*)d_ws + part_bytes);
    cham_min_kernel<<<dim3(2 * BB * JC), dim3(BLK), 0, stream>>>(est, gt, part);
    finalize_kernel<<<dim3(FIN_BLOCKS), dim3(BLK), 0, stream>>>(
        est, gt, lest, lab, part, bsum);
    sum_kernel<<<dim3(1), dim3(BLK), 0, stream>>>(bsum, out);
  } else {
    hipMemsetAsync(out, 0, sizeof(float), stream);
    chamfer_bce_kernel<<<dim3(2 * BB * (NN / BLK)), dim3(BLK), 0, stream>>>(
        est, gt, lest, lab, out);
  }
}

// Round 4
// 31.085 us; speedup vs baseline: 2.3514x; 1.0858x over previous
//
#include <hip/hip_runtime.h>
#include <hip/hip_bf16.h>
#include <hip/hip_fp16.h>
#include <math.h>

#define BB 32
#define NN 2048
#define BLK 256
#define JC 16
#define JCH (NN / JC)   // 128 targets per block (4 j-tiles of 32)
#define BBNN (BB * NN)  // 65536
#define FIN_BLOCKS ((2 * BBNN) / BLK)  // 512

typedef _Float16 f16x8 __attribute__((ext_vector_type(8)));
typedef float f32x16 __attribute__((ext_vector_type(16)));

__device__ __forceinline__ unsigned pk2h(float a, float b) {
  union { _Float16 h[2]; unsigned u; } v;
  v.h[0] = (_Float16)a; v.h[1] = (_Float16)b;
  return v.u;
}

__device__ __forceinline__ float min16(const f32x16& d) {
  float a0 = fminf(fminf(d[0], d[1]), d[2]);
  float a1 = fminf(fminf(d[3], d[4]), d[5]);
  float a2 = fminf(fminf(d[6], d[7]), d[8]);
  float a3 = fminf(fminf(d[9], d[10]), d[11]);
  float a4 = fminf(fminf(d[12], d[13]), d[14]);
  float b0 = fminf(fminf(a0, a1), a2);
  float b1 = fminf(fminf(a3, a4), d[15]);
  return fminf(b0, b1);
}

// Pass 1 (MFMA): block (dir,b,jc). Targets = MFMA rows (A), queries = cols (B).
// A lane frag: (y0,y1,y2,h, 0..) duplicated in both k-halves; B: (-x0,-x1,-x2,1).
// D[j][i] = 2*(h - x.y) = |y|^2 - 2 x.y = t. Per-lane reg-min over 16 rows,
// shfl_xor(32) merges the halves -> min over the 32-row j-tile per query col.
// part[(jc*2+dir)*BBNN + b*NN + i] = min_j t. Also zeroes out[0] (block 0).
__global__ __launch_bounds__(BLK) void cham_min_mfma(
    const float* __restrict__ est, const float* __restrict__ gt,
    float* __restrict__ part, float* __restrict__ out) {
  int id = blockIdx.x;
  int jc = id % JC; id /= JC;
  int b = id % BB;
  int dir = id / BB;

  if (blockIdx.x == 0 && threadIdx.x == 0) out[0] = 0.0f;

  const float* X = dir ? gt : est;   // queries
  const float* Y = dir ? est : gt;   // targets

  __shared__ uint4 afrag[4][64];     // 4 j-tiles x 64 lanes x 16B = 4 KB
  {
    int t = threadIdx.x;
    int jt = t >> 6, l = t & 63;
    int j = jc * JCH + jt * 32 + (l & 31);
    const float* yp = Y + ((size_t)b * NN + j) * 3;
    float y0 = yp[0], y1 = yp[1], y2 = yp[2];
    float h = 0.5f * (y0 * y0 + y1 * y1 + y2 * y2);
    uint4 u;
    u.x = pk2h(y0, y1);
    u.y = pk2h(y2, h);
    u.z = 0u; u.w = 0u;
    afrag[jt][l] = u;                // both lane halves carry the same data
  }
  __syncthreads();

  int lane = threadIdx.x & 63;
  int w = threadIdx.x >> 6;

  f16x8 afr[4];
#pragma unroll
  for (int jt = 0; jt < 4; ++jt)
    afr[jt] = __builtin_bit_cast(f16x8, afrag[jt][lane]);

  const f32x16 zz = {0.f, 0.f, 0.f, 0.f, 0.f, 0.f, 0.f, 0.f,
                     0.f, 0.f, 0.f, 0.f, 0.f, 0.f, 0.f, 0.f};

  float* prow = part + ((size_t)(jc * 2 + dir) * BB + b) * NN;

  for (int n = 0; n < 16; ++n) {     // 16 i-groups of 32 queries per wave
    int q = (w * 16 + n) * 32 + (lane & 31);
    const float* xp = X + ((size_t)b * NN + q) * 3;
    float x0 = xp[0], x1 = xp[1], x2v = xp[2];
    uint4 ub;
    ub.x = pk2h(-x0, -x1);
    ub.y = pk2h(-x2v, 1.0f);
    ub.z = 0u; ub.w = 0u;
    f16x8 bf = __builtin_bit_cast(f16x8, ub);

    f32x16 d0 = __builtin_amdgcn_mfma_f32_32x32x16_f16(afr[0], bf, zz, 0, 0, 0);
    f32x16 d1 = __builtin_amdgcn_mfma_f32_32x32x16_f16(afr[1], bf, zz, 0, 0, 0);
    float mnq = fminf(min16(d0), min16(d1));
    f32x16 d2 = __builtin_amdgcn_mfma_f32_32x32x16_f16(afr[2], bf, zz, 0, 0, 0);
    f32x16 d3 = __builtin_amdgcn_mfma_f32_32x32x16_f16(afr[3], bf, zz, 0, 0, 0);
    mnq = fminf(mnq, fminf(min16(d2), min16(d3)));

    mnq = fminf(mnq, __shfl_xor(mnq, 32, 64));  // merge lane halves (row 16-31)
    if (lane < 32) prow[q] = mnq;
  }
}

// Pass 2: min over 16 jc-partials, d2 = max(x^2 + t, 0) [t = |y|^2 - 2 x.y],
// fuse BCE on dir==0, block-reduce, atomicAdd into out (zeroed by pass 1).
__global__ __launch_bounds__(BLK) void finalize_kernel(
    const float* __restrict__ est, const float* __restrict__ gt,
    const float* __restrict__ lest, const float* __restrict__ lab,
    const float* __restrict__ part, float* __restrict__ out) {
  int q = blockIdx.x * BLK + threadIdx.x;  // [0, 2*BBNN)
  int dir = q / BBNN;                      // uniform per block
  int r = q % BBNN;

  float t = part[(size_t)dir * BBNN + r];
#pragma unroll
  for (int jc = 1; jc < JC; ++jc)
    t = fminf(t, part[(size_t)(jc * 2 + dir) * BBNN + r]);

  const float* xp = (dir ? gt : est) + (size_t)r * 3;
  float ex = xp[0], ey = xp[1], ez = xp[2];
  float x2 = fmaf(ex, ex, fmaf(ey, ey, ez * ez));
  float val = fmaxf(x2 + t, 0.0f);

  if (!dir) {  // wave-uniform branch
    float z = lest[r], tt = lab[r];
    val += fmaxf(z, 0.0f) - z * tt + log1pf(expf(-fabsf(z)));
  }

  for (int off = 32; off > 0; off >>= 1) val += __shfl_down(val, off);
  __shared__ float wsum[BLK / 64];
  int lane = threadIdx.x & 63;
  int wid = threadIdx.x >> 6;
  if (lane == 0) wsum[wid] = val;
  __syncthreads();
  if (threadIdx.x == 0) {
    float s = 0.0f;
#pragma unroll
    for (int wv = 0; wv < BLK / 64; ++wv) s += wsum[wv];
    atomicAdd(out, s * (1.0f / ((float)BB * (float)NN)));
  }
}

// Fallback (proven-correct R1 kernel) if ws is too small.
__global__ __launch_bounds__(BLK) void chamfer_bce_kernel(
    const float* __restrict__ est, const float* __restrict__ gt,
    const float* __restrict__ lest, const float* __restrict__ lab,
    float* __restrict__ out) {
  int bid = blockIdx.x;
  int dir = (bid >= BB * (NN / BLK)) ? 1 : 0;
  int id = dir ? (bid - BB * (NN / BLK)) : bid;
  int b = id / (NN / BLK);
  int tile = id % (NN / BLK);
  const float* X = dir ? gt : est;
  const float* Y = dir ? est : gt;
  __shared__ float4 sy[NN];
  const float* yb = Y + (size_t)b * NN * 3;
  for (int j = threadIdx.x; j < NN; j += BLK)
    sy[j] = make_float4(yb[3 * j], yb[3 * j + 1], yb[3 * j + 2], 0.0f);
  __syncthreads();
  int i = tile * BLK + threadIdx.x;
  const float* xb = X + (size_t)b * NN * 3 + (size_t)3 * i;
  float ex = xb[0], ey = xb[1], ez = xb[2];
  float m0 = 3.4e38f, m1 = 3.4e38f, m2 = 3.4e38f, m3 = 3.4e38f;
#pragma unroll 4
  for (int j = 0; j < NN; j += 4) {
    float4 p0 = sy[j], p1 = sy[j + 1], p2 = sy[j + 2], p3 = sy[j + 3];
    { float dx = ex - p0.x, dy = ey - p0.y, dz = ez - p0.z;
      m0 = fminf(m0, fmaf(dx, dx, fmaf(dy, dy, dz * dz))); }
    { float dx = ex - p1.x, dy = ey - p1.y, dz = ez - p1.z;
      m1 = fminf(m1, fmaf(dx, dx, fmaf(dy, dy, dz * dz))); }
    { float dx = ex - p2.x, dy = ey - p2.y, dz = ez - p2.z;
      m2 = fminf(m2, fmaf(dx, dx, fmaf(dy, dy, dz * dz))); }
    { float dx = ex - p3.x, dy = ey - p3.y, dz = ez - p3.z;
      m3 = fminf(m3, fmaf(dx, dx, fmaf(dy, dy, dz * dz))); }
  }
  float val = fminf(fminf(m0, m1), fminf(m2, m3));
  if (!dir) {
    float z = lest[(size_t)b * NN + i];
    float t = lab[(size_t)b * NN + i];
    val += fmaxf(z, 0.0f) - z * t + log1pf(expf(-fabsf(z)));
  }
  for (int off = 32; off > 0; off >>= 1) val += __shfl_down(val, off);
  __shared__ float wsum[BLK / 64];
  int lane = threadIdx.x & 63;
  int wid = threadIdx.x >> 6;
  if (lane == 0) wsum[wid] = val;
  __syncthreads();
  if (threadIdx.x == 0) {
    float s = 0.0f;
#pragma unroll
    for (int w = 0; w < BLK / 64; ++w) s += wsum[w];
    atomicAdd(out, s * (1.0f / ((float)BB * (float)NN)));
  }
}

extern "C" void kernel_launch(void* const* d_in, const int* in_sizes, int n_in,
                              void* d_out, int out_size, void* d_ws, size_t ws_size,
                              hipStream_t stream) {
  const float* est = (const float*)d_in[0];
  const float* gt = (const float*)d_in[1];
  const float* lest = (const float*)d_in[2];
  const float* lab = (const float*)d_in[3];
  float* out = (float*)d_out;

  const size_t part_bytes = (size_t)JC * 2 * BBNN * sizeof(float);  // 8 MB
  if (ws_size >= part_bytes) {
    float* part = (float*)d_ws;
    cham_min_mfma<<<dim3(2 * BB * JC), dim3(BLK), 0, stream>>>(est, gt, part, out);
    finalize_kernel<<<dim3(FIN_BLOCKS), dim3(BLK), 0, stream>>>(
        est, gt, lest, lab, part, out);
  } else {
    hipMemsetAsync(out, 0, sizeof(float), stream);
    chamfer_bce_kernel<<<dim3(2 * BB * (NN / BLK)), dim3(BLK), 0, stream>>>(
        est, gt, lest, lab, out);
  }
}

// Round 5
// 21.830 us; speedup vs baseline: 3.3483x; 1.4240x over previous
//
#include <hip/hip_runtime.h>
#include <hip/hip_bf16.h>
#include <hip/hip_fp16.h>
#include <math.h>

#define BB 32
#define NN 2048
#define BLK 256
#define ITILE 128                       // queries per block (32 per wave)
#define NTIL (NN / ITILE)               // 16
#define NBLK (2 * BB * NTIL)            // 1024
#define JT (NN / 32)                    // 64 j-tiles of 32 targets

typedef _Float16 f16x8 __attribute__((ext_vector_type(8)));
typedef float f32x16 __attribute__((ext_vector_type(16)));

__device__ __forceinline__ unsigned pk2h(float a, float b) {
  union { _Float16 h[2]; unsigned u; } v;
  v.h[0] = (_Float16)a; v.h[1] = (_Float16)b;
  return v.u;
}

__device__ __forceinline__ float min16(const f32x16& d) {
  // 3-way groupings fold to v_min3_f32
  float a0 = fminf(fminf(d[0], d[1]), d[2]);
  float a1 = fminf(fminf(d[3], d[4]), d[5]);
  float a2 = fminf(fminf(d[6], d[7]), d[8]);
  float a3 = fminf(fminf(d[9], d[10]), d[11]);
  float a4 = fminf(fminf(d[12], d[13]), d[14]);
  float b0 = fminf(fminf(a0, a1), a2);
  float b1 = fminf(fminf(a3, a4), d[15]);
  return fminf(b0, b1);
}

// Fused chamfer: block (dir, b, it). Stages ALL 2048 targets of (dir,b) as
// packed A-fragments (y0,y1,y2,|y|^2/2 duplicated in both k-halves); each
// wave owns 32 queries (B-frag: -x0,-x1,-x2,1) and loops 64 j-tiles:
// D[j][i] = |y|^2 - 2 x.y = t. Running per-lane min over 16 rows/MFMA,
// one shfl_xor(32) merges halves -> full min over 2048 targets.
// Epilogue: d2 = max(x^2 + t, 0) + BCE (dir==0), block sum -> bsum.
__global__ __launch_bounds__(BLK) void cham_fused(
    const float* __restrict__ est, const float* __restrict__ gt,
    const float* __restrict__ lest, const float* __restrict__ lab,
    float* __restrict__ bsum) {
  int id = blockIdx.x;
  int it = id % NTIL; id /= NTIL;
  int b = id % BB;
  int dir = id / BB;

  const float* X = dir ? gt : est;   // queries
  const float* Y = dir ? est : gt;   // targets

  __shared__ uint4 sy[JT][32];       // 32 KB: 64 j-tiles x 32 rows x 16B

  const float* yb = Y + (size_t)b * NN * 3;
  for (int j = threadIdx.x; j < NN; j += BLK) {
    float y0 = yb[3 * j], y1 = yb[3 * j + 1], y2 = yb[3 * j + 2];
    float h = 0.5f * (y0 * y0 + y1 * y1 + y2 * y2);
    uint4 u;
    u.x = pk2h(y0, y1);
    u.y = pk2h(y2, h);
    u.z = 0u; u.w = 0u;
    sy[j >> 5][j & 31] = u;
  }
  __syncthreads();

  int lane = threadIdx.x & 63;
  int w = threadIdx.x >> 6;
  int q = it * ITILE + w * 32 + (lane & 31);

  const float* xp = X + ((size_t)b * NN + q) * 3;
  float x0 = xp[0], x1 = xp[1], x2 = xp[2];
  uint4 ub;
  ub.x = pk2h(-x0, -x1);
  ub.y = pk2h(-x2, 1.0f);
  ub.z = 0u; ub.w = 0u;
  f16x8 bf = __builtin_bit_cast(f16x8, ub);

  const f32x16 zz = {0.f, 0.f, 0.f, 0.f, 0.f, 0.f, 0.f, 0.f,
                     0.f, 0.f, 0.f, 0.f, 0.f, 0.f, 0.f, 0.f};

  float mn = 3.4e38f;
#pragma unroll 4
  for (int jt = 0; jt < JT; ++jt) {
    f16x8 af = __builtin_bit_cast(f16x8, sy[jt][lane & 31]);
    f32x16 d = __builtin_amdgcn_mfma_f32_32x32x16_f16(af, bf, zz, 0, 0, 0);
    mn = fminf(mn, min16(d));
  }
  mn = fminf(mn, __shfl_xor(mn, 32, 64));  // merge row halves 0-15 / 16-31

  float x2n = fmaf(x0, x0, fmaf(x1, x1, x2 * x2));
  float val = fmaxf(x2n + mn, 0.0f);
  if (!dir) {  // wave-uniform branch: fuse BCE for element (b, q)
    float z = lest[(size_t)b * NN + q];
    float tt = lab[(size_t)b * NN + q];
    val += fmaxf(z, 0.0f) - z * tt + log1pf(expf(-fabsf(z)));
  }
  if (lane >= 32) val = 0.0f;  // upper half duplicates lower half

  for (int off = 32; off > 0; off >>= 1) val += __shfl_down(val, off);
  __shared__ float wsum[BLK / 64];
  if (lane == 0) wsum[w] = val;
  __syncthreads();
  if (threadIdx.x == 0)
    bsum[blockIdx.x] = wsum[0] + wsum[1] + wsum[2] + wsum[3];
}

// Final: sum 1024 block partials, scale, store scalar. Deterministic.
__global__ __launch_bounds__(BLK) void sum_kernel(
    const float* __restrict__ bsum, float* __restrict__ out) {
  float val = 0.0f;
#pragma unroll
  for (int k = 0; k < NBLK / BLK; ++k) val += bsum[threadIdx.x + k * BLK];
  for (int off = 32; off > 0; off >>= 1) val += __shfl_down(val, off);
  __shared__ float wsum[BLK / 64];
  int lane = threadIdx.x & 63;
  int wid = threadIdx.x >> 6;
  if (lane == 0) wsum[wid] = val;
  __syncthreads();
  if (threadIdx.x == 0) {
    float s = 0.0f;
#pragma unroll
    for (int wv = 0; wv < BLK / 64; ++wv) s += wsum[wv];
    out[0] = s * (1.0f / ((float)BB * (float)NN));
  }
}

// Fallback (proven-correct R1 kernel) if ws is too small.
__global__ __launch_bounds__(BLK) void chamfer_bce_kernel(
    const float* __restrict__ est, const float* __restrict__ gt,
    const float* __restrict__ lest, const float* __restrict__ lab,
    float* __restrict__ out) {
  int bid = blockIdx.x;
  int dir = (bid >= BB * (NN / BLK)) ? 1 : 0;
  int id = dir ? (bid - BB * (NN / BLK)) : bid;
  int b = id / (NN / BLK);
  int tile = id % (NN / BLK);
  const float* X = dir ? gt : est;
  const float* Y = dir ? est : gt;
  __shared__ float4 sy[NN];
  const float* yb = Y + (size_t)b * NN * 3;
  for (int j = threadIdx.x; j < NN; j += BLK)
    sy[j] = make_float4(yb[3 * j], yb[3 * j + 1], yb[3 * j + 2], 0.0f);
  __syncthreads();
  int i = tile * BLK + threadIdx.x;
  const float* xb = X + (size_t)b * NN * 3 + (size_t)3 * i;
  float ex = xb[0], ey = xb[1], ez = xb[2];
  float m0 = 3.4e38f, m1 = 3.4e38f, m2 = 3.4e38f, m3 = 3.4e38f;
#pragma unroll 4
  for (int j = 0; j < NN; j += 4) {
    float4 p0 = sy[j], p1 = sy[j + 1], p2 = sy[j + 2], p3 = sy[j + 3];
    { float dx = ex - p0.x, dy = ey - p0.y, dz = ez - p0.z;
      m0 = fminf(m0, fmaf(dx, dx, fmaf(dy, dy, dz * dz))); }
    { float dx = ex - p1.x, dy = ey - p1.y, dz = ez - p1.z;
      m1 = fminf(m1, fmaf(dx, dx, fmaf(dy, dy, dz * dz))); }
    { float dx = ex - p2.x, dy = ey - p2.y, dz = ez - p2.z;
      m2 = fminf(m2, fmaf(dx, dx, fmaf(dy, dy, dz * dz))); }
    { float dx = ex - p3.x, dy = ey - p3.y, dz = ez - p3.z;
      m3 = fminf(m3, fmaf(dx, dx, fmaf(dy, dy, dz * dz))); }
  }
  float val = fminf(fminf(m0, m1), fminf(m2, m3));
  if (!dir) {
    float z = lest[(size_t)b * NN + i];
    float t = lab[(size_t)b * NN + i];
    val += fmaxf(z, 0.0f) - z * t + log1pf(expf(-fabsf(z)));
  }
  for (int off = 32; off > 0; off >>= 1) val += __shfl_down(val, off);
  __shared__ float wsum[BLK / 64];
  int lane = threadIdx.x & 63;
  int wid = threadIdx.x >> 6;
  if (lane == 0) wsum[wid] = val;
  __syncthreads();
  if (threadIdx.x == 0) {
    float s = 0.0f;
#pragma unroll
    for (int w = 0; w < BLK / 64; ++w) s += wsum[w];
    atomicAdd(out, s * (1.0f / ((float)BB * (float)NN)));
  }
}

extern "C" void kernel_launch(void* const* d_in, const int* in_sizes, int n_in,
                              void* d_out, int out_size, void* d_ws, size_t ws_size,
                              hipStream_t stream) {
  const float* est = (const float*)d_in[0];
  const float* gt = (const float*)d_in[1];
  const float* lest = (const float*)d_in[2];
  const float* lab = (const float*)d_in[3];
  float* out = (float*)d_out;

  const size_t need = (size_t)NBLK * sizeof(float);  // 4 KB
  if (ws_size >= need) {
    float* bsum = (float*)d_ws;
    cham_fused<<<dim3(NBLK), dim3(BLK), 0, stream>>>(est, gt, lest, lab, bsum);
    sum_kernel<<<dim3(1), dim3(BLK), 0, stream>>>(bsum, out);
  } else {
    hipMemsetAsync(out, 0, sizeof(float), stream);
    chamfer_bce_kernel<<<dim3(2 * BB * (NN / BLK)), dim3(BLK), 0, stream>>>(
        est, gt, lest, lab, out);
  }
}